// Round 14
// baseline (1056.619 us; speedup 1.0000x reference)
//
#include <hip/hip_runtime.h>

// ---------------------------------------------------------------------------
// Encoder: 3-layer HeteroGraphConv(3 edge types) -> FC -> ReLU -> BatchNorm
// Round 14: revert NT hints (R13: FETCH rose, agg +8us each -> theory
// falsified). NEW: radix-structured build:
//   * coarse_hist stores per-block bin counts (no global atomics)
//   * blk_scan: per-(type,bin) prefix over blocks + totals (deterministic)
//   * scatter_coarse: loads counts/bases, single edge pass, zero atomics
//   * rest = R12: fp16 pipeline, packed 4B records, fused mfma_layer
// ---------------------------------------------------------------------------

#define EPSV 1e-5f
#define CH 4096      // edges per block in coarse passes
#define MAXNB 512    // max coarse bins (N <= 131072; also requires N < 2^20)

typedef _Float16 h2v __attribute__((ext_vector_type(2)));
typedef _Float16 f16x8 __attribute__((ext_vector_type(8)));  // MFMA A/B frag
typedef __attribute__((ext_vector_type(4))) float f4v;       // 4 f32 acc

// ---------------- build phase 1: per-block coarse histograms ---------------
__global__ void coarse_hist(const int* __restrict__ src, const int* __restrict__ dst,
                            int* __restrict__ bhd, int* __restrict__ bhs,
                            int E, int NB, int nblk) {
    __shared__ int hd[MAXNB], hs[MAXNB];
    const int t = blockIdx.y;
    const int blk = blockIdx.x;
    for (int i = threadIdx.x; i < MAXNB; i += 256) { hd[i] = 0; hs[i] = 0; }
    __syncthreads();
    int base = blk * CH;
    int end = base + CH < E ? base + CH : E;
    const int* sp = src + (size_t)t * E;
    const int* dp = dst + (size_t)t * E;
    for (int i = base + threadIdx.x; i < end; i += 256) {
        atomicAdd(&hd[dp[i] >> 8], 1);
        atomicAdd(&hs[sp[i] >> 8], 1);
    }
    __syncthreads();
    for (int b = threadIdx.x; b < NB; b += 256) {
        size_t o = (size_t)(t * NB + b) * nblk + blk;
        bhd[o] = hd[b];
        bhs[o] = hs[b];
    }
}

// ---------------- build phase 2a: prefix over blocks per (type,bin) --------
__global__ void blk_scan(const int* __restrict__ bhd, const int* __restrict__ bhs,
                         int* __restrict__ bpd, int* __restrict__ bps,
                         int* __restrict__ chd, int* __restrict__ chs,
                         int NB, int nblk) {
    int id = blockIdx.x * 256 + threadIdx.x;   // 0 .. 2*3*NB-1
    int half = 3 * NB;
    if (id >= 2 * half) return;
    bool isS = id >= half;
    int r = isS ? id - half : id;
    const int* cnt = isS ? bhs : bhd;
    int* pfx = isS ? bps : bpd;
    int* tot = isS ? chs : chd;
    size_t base = (size_t)r * nblk;
    int run = 0;
    for (int b = 0; b < nblk; ++b) {
        int v = cnt[base + b];
        pfx[base + b] = run;
        run += v;
    }
    tot[r] = run;
}

// ---------------- build phase 2b: scan coarse bins -> offsets --------------
__global__ void scan_off(const int* __restrict__ chd, const int* __restrict__ chs,
                         int* __restrict__ offd, int* __restrict__ offs,
                         int* __restrict__ rowptr, int NB, int N, int E) {
    __shared__ int s[MAXNB];
    int tid = threadIdx.x;
    for (int a = 0; a < 6; ++a) {
        const int* h = (a < 3) ? chd + a * NB : chs + (a - 3) * NB;
        int* off = (a < 3) ? offd + a * (NB + 1) : offs + (a - 3) * (NB + 1);
        s[tid] = (tid < NB) ? h[tid] : 0;
        __syncthreads();
        for (int o = 1; o < MAXNB; o <<= 1) {
            int v = (tid >= o) ? s[tid - o] : 0;
            __syncthreads();
            s[tid] += v;
            __syncthreads();
        }
        if (tid < NB) {
            off[tid + 1] = s[tid];
            if (tid == 0) off[0] = 0;
        }
        __syncthreads();
    }
    if (tid < 3) rowptr[tid * (N + 1) + N] = E;
}

// ---------------- build phase 3: scatter (single pass, no atomics) ---------
__launch_bounds__(256)
__global__ void scatter_coarse(const int* __restrict__ src, const int* __restrict__ dst,
                               const int* __restrict__ bhd, const int* __restrict__ bhs,
                               const int* __restrict__ bpd, const int* __restrict__ bps,
                               const int* __restrict__ offd, const int* __restrict__ offs,
                               int* __restrict__ dbuf, unsigned char* __restrict__ sbuf,
                               int E, int NB, int nblk) {
    __shared__ int hd[MAXNB], hs[MAXNB];     // local cursors
    __shared__ int lod[MAXNB], los[MAXNB];   // inclusive scans
    __shared__ int bd[MAXNB], bs[MAXNB];     // global bases
    __shared__ int rbi[CH];
    __shared__ unsigned char rbs[CH];
    const int tid = threadIdx.x;
    const int t = blockIdx.y;
    const int blk = blockIdx.x;
    const int base = blk * CH;
    const int end = base + CH < E ? base + CH : E;
    const int cnt = end - base;
    const int* sp = src + (size_t)t * E;
    const int* dp = dst + (size_t)t * E;

    // load this block's counts + global bases
    for (int b = tid; b < MAXNB; b += 256) {
        if (b < NB) {
            size_t o = (size_t)(t * NB + b) * nblk + blk;
            int cd = bhd[o], cs2 = bhs[o];
            hd[b] = cd;
            hs[b] = cs2;
            bd[b] = offd[t * (NB + 1) + b] + bpd[o];
            bs[b] = offs[t * (NB + 1) + b] + bps[o];
        } else {
            hd[b] = 0;
            hs[b] = 0;
        }
    }
    lod[tid] = hd[tid]; lod[tid + 256] = hd[tid + 256];
    los[tid] = hs[tid]; los[tid + 256] = hs[tid + 256];
    __syncthreads();
    for (int o = 1; o < MAXNB; o <<= 1) {
        int a0 = lod[tid], a1 = lod[tid + 256];
        int b0 = los[tid], b1 = los[tid + 256];
        int p0 = (tid >= o) ? lod[tid - o] : 0;
        int p1 = lod[tid + 256 - o];
        int q0 = (tid >= o) ? los[tid - o] : 0;
        int q1 = los[tid + 256 - o];
        __syncthreads();
        lod[tid] = a0 + p0; lod[tid + 256] = a1 + p1;
        los[tid] = b0 + q0; los[tid + 256] = b1 + q1;
        __syncthreads();
    }
    hd[tid] = lod[tid] - hd[tid]; hd[tid + 256] = lod[tid + 256] - hd[tid + 256];
    hs[tid] = los[tid] - hs[tid]; hs[tid + 256] = los[tid + 256] - hs[tid + 256];
    __syncthreads();
    for (int i = base + tid; i < end; i += 256) {
        int sv = sp[i], dv = dp[i];
        int lp = atomicAdd(&hd[dv >> 8], 1);
        rbi[lp] = (sv << 8) | (dv & 255);
        int ls = atomicAdd(&hs[sv >> 8], 1);
        rbs[ls] = (unsigned char)(sv & 255);
    }
    __syncthreads();
    for (int i = tid; i < cnt; i += 256) {
        int lo = 0, hi = NB - 1;
        while (lo < hi) { int mid = (lo + hi) >> 1; if (lod[mid] > i) hi = mid; else lo = mid + 1; }
        int excl = lo ? lod[lo - 1] : 0;
        dbuf[(size_t)t * E + bd[lo] + (i - excl)] = rbi[i];
    }
    for (int i = tid; i < cnt; i += 256) {
        int lo = 0, hi = NB - 1;
        while (lo < hi) { int mid = (lo + hi) >> 1; if (los[mid] > i) hi = mid; else lo = mid + 1; }
        int excl = lo ? los[lo - 1] : 0;
        sbuf[(size_t)t * E + bs[lo] + (i - excl)] = rbs[i];
    }
}

// ---------------- build phase 4a: fine histogram by src -> dro (FIRST) -----
__global__ void fine_src(const unsigned char* __restrict__ sbuf, const int* __restrict__ offs,
                         float* __restrict__ dro, int E, int N, int NB) {
    __shared__ int h[256];
    int b = blockIdx.x, t = blockIdx.y;
    int tid = threadIdx.x;
    h[tid] = 0;
    __syncthreads();
    int beg = offs[t * (NB + 1) + b], end = offs[t * (NB + 1) + b + 1];
    const unsigned char* sp = sbuf + (size_t)t * E;
    for (int i = beg + tid; i < end; i += 256) atomicAdd(&h[sp[i]], 1);
    __syncthreads();
    int node = b * 256 + tid;
    if (node < N) {
        int dg = h[tid] < 1 ? 1 : h[tid];
        dro[(size_t)t * N + node] = rsqrtf((float)dg);
    }
}

// ---------------- build phase 4b: fine sort by dst -> records src|wq<<20 ---
#define FDCAP 6656
__global__ void fine_dst(const int* __restrict__ dbuf, const int* __restrict__ offd,
                         const float* __restrict__ dro, int* __restrict__ erec,
                         int* __restrict__ rowptr, float* __restrict__ dri,
                         int E, int N, int NB) {
    __shared__ int h[256], sc[256], cur[256];
    __shared__ int rb[FDCAP];
    int b = blockIdx.x, t = blockIdx.y;
    int tid = threadIdx.x;
    h[tid] = 0;
    __syncthreads();
    int beg = offd[t * (NB + 1) + b], end = offd[t * (NB + 1) + b + 1];
    int cnt = end - beg;
    const int* dp = dbuf + (size_t)t * E;
    const float* drt = dro + (size_t)t * N;
    for (int i = beg + tid; i < end; i += 256) atomicAdd(&h[dp[i] & 255], 1);
    __syncthreads();
    sc[tid] = h[tid];
    __syncthreads();
    for (int o = 1; o < 256; o <<= 1) {
        int v = (tid >= o) ? sc[tid - o] : 0;
        __syncthreads();
        sc[tid] += v;
        __syncthreads();
    }
    int excl = sc[tid] - h[tid];
    cur[tid] = excl;
    int node = b * 256 + tid;
    if (node < N) {
        rowptr[t * (N + 1) + node] = beg + excl;
        int dg = h[tid] < 1 ? 1 : h[tid];
        dri[(size_t)t * N + node] = rsqrtf((float)dg);
    }
    __syncthreads();
    if (cnt <= FDCAP) {
        for (int i = beg + tid; i < end; i += 256) {
            int v = dp[i];
            int p = atomicAdd(&cur[v & 255], 1);
            rb[p] = v >> 8;
        }
        __syncthreads();
        for (int i = tid; i < cnt; i += 256) {
            int sv = rb[i];
            int wq = (int)(drt[sv] * 4095.0f + 0.5f);   // 12-bit weight
            erec[(size_t)t * E + beg + i] = sv | (wq << 20);
        }
    } else {
        for (int i = beg + tid; i < end; i += 256) {
            int v = dp[i];
            int sv = v >> 8;
            int wq = (int)(drt[sv] * 4095.0f + 0.5f);
            int p = beg + atomicAdd(&cur[v & 255], 1);
            erec[(size_t)t * E + p] = sv | (wq << 20);
        }
    }
}

// ---------------- fp16 helpers ----------------
__device__ __forceinline__ h2v ash2(unsigned u) {
    union { unsigned u; h2v h; } c;
    c.u = u;
    return c.h;
}
__device__ __forceinline__ unsigned packh2(float lo, float hi) {
    union { h2v h; unsigned u; } c;
    c.h = (h2v){(_Float16)lo, (_Float16)hi};
    return c.u;
}
__device__ __forceinline__ unsigned short f16b(float f) {
    union { _Float16 h; unsigned short s; } c;
    c.h = (_Float16)f;
    return c.s;
}

// ---------------- fp32 -> fp16 convert (initial x copy) --------------------
__global__ void cvt_f16(const float* __restrict__ h, unsigned short* __restrict__ h2,
                        int total8) {
    int i = blockIdx.x * 256 + threadIdx.x;
    if (i >= total8) return;
    const float4* hp = (const float4*)h + (size_t)i * 2;
    float4 v0 = hp[0], v1 = hp[1];
    uint4 o;
    o.x = packh2(v0.x, v0.y);
    o.y = packh2(v0.z, v0.w);
    o.z = packh2(v1.x, v1.y);
    o.w = packh2(v1.z, v1.w);
    ((uint4*)h2)[i] = o;
}

// ---------------- weight packing: fragment-ordered fp16 --------------------
__global__ void pack_w(const float* __restrict__ gcW0, const float* __restrict__ gcW,
                       const float* __restrict__ fcW, unsigned short* __restrict__ Wg,
                       unsigned short* __restrict__ Wf) {
    int mat = blockIdx.x;   // 0..8 = gc (l*3+e), 9..11 = fc layer
    const float* srcp;
    unsigned short* dstp;
    if (mat < 9) {
        int l = mat / 3, e = mat % 3;
        srcp = (l == 0) ? gcW0 + (size_t)e * 16384
                        : gcW + ((size_t)(l - 1) * 3 + e) * 16384;
        dstp = Wg + (size_t)mat * 16384;
    } else {
        srcp = fcW + (size_t)(mat - 9) * 16384;
        dstp = Wf + (size_t)(mat - 9) * 16384;
    }
    for (int p = threadIdx.x; p < 16384; p += 256) {
        int j = p & 7;
        int ln = (p >> 3) & 63;
        int nt = (p >> 9) & 7;
        int ks = p >> 12;
        int k = ks * 32 + (ln >> 4) * 8 + j;
        int n = nt * 16 + (ln & 15);
        dstp[p] = f16b(srcp[k * 128 + n]);
    }
}

// ---------------- aggregation: fp16 gather, packed half2 FMA ---------------
// 16 lanes/node, uint4 (8 fp16) per lane. Records = src | wq<<20 (w = wq/4095).
// AFF==1: input h2 is PRE-BN; BN affine folded via linearity (wacc term).
template <int AFF>
__launch_bounds__(256)
__global__ void agg_kernel(const unsigned short* __restrict__ h2, const int* __restrict__ rowptrB,
                           const int* __restrict__ erecB, const float* __restrict__ driB,
                           const float* __restrict__ bnsum, const float* __restrict__ gamma,
                           const float* __restrict__ beta, float invn,
                           unsigned short* __restrict__ zB, int N, int E) {
    __shared__ float lss[256];
    if (AFF) {
        int tid = threadIdx.x;
        if (tid < 128) {
            float mean = bnsum[tid] * invn;
            float var = bnsum[128 + tid] * invn - mean * mean;
            float sc = gamma[tid] * rsqrtf(var + EPSV);
            lss[tid] = sc;
            lss[128 + tid] = beta[tid] - mean * sc;
        }
        __syncthreads();
    }
    const int e = blockIdx.y;
    const int* rowptr = rowptrB + e * (N + 1);
    const int* erec = erecB + (size_t)e * E;
    const float* dri = driB + (size_t)e * N;
    unsigned short* z = zB + (size_t)e * N * 128;

    int idx = blockIdx.x * 256 + threadIdx.x;
    int node = idx >> 4;
    int lq = idx & 15;
    if (node >= N) return;
    int beg = rowptr[node], end = rowptr[node + 1];
    const uint4* hp = (const uint4*)h2 + lq;   // row s at hp[s*16]
    h2v ac0 = (h2v)0, ac1 = (h2v)0, ac2 = (h2v)0, ac3 = (h2v)0;
    float wacc = 0.f;
    const float IW = 1.0f / 4095.0f;

    int j = beg;
    for (; j + 8 <= end; j += 8) {
        int r[8];
#pragma unroll
        for (int q = 0; q < 8; ++q) r[q] = erec[j + q];
        uint4 u[8];
#pragma unroll
        for (int q = 0; q < 8; ++q) u[q] = hp[(size_t)(r[q] & 0xFFFFF) * 16];
#pragma unroll
        for (int q = 0; q < 8; ++q) {
            float wf = (float)((unsigned)r[q] >> 20) * IW;
            if (AFF) wacc += wf;
            _Float16 wh = (_Float16)wf;
            h2v wp = (h2v){wh, wh};
            ac0 = ash2(u[q].x) * wp + ac0;
            ac1 = ash2(u[q].y) * wp + ac1;
            ac2 = ash2(u[q].z) * wp + ac2;
            ac3 = ash2(u[q].w) * wp + ac3;
        }
    }
    for (; j + 4 <= end; j += 4) {
        int r[4];
#pragma unroll
        for (int q = 0; q < 4; ++q) r[q] = erec[j + q];
        uint4 u[4];
#pragma unroll
        for (int q = 0; q < 4; ++q) u[q] = hp[(size_t)(r[q] & 0xFFFFF) * 16];
#pragma unroll
        for (int q = 0; q < 4; ++q) {
            float wf = (float)((unsigned)r[q] >> 20) * IW;
            if (AFF) wacc += wf;
            _Float16 wh = (_Float16)wf;
            h2v wp = (h2v){wh, wh};
            ac0 = ash2(u[q].x) * wp + ac0;
            ac1 = ash2(u[q].y) * wp + ac1;
            ac2 = ash2(u[q].z) * wp + ac2;
            ac3 = ash2(u[q].w) * wp + ac3;
        }
    }
    for (; j < end; ++j) {
        int r0 = erec[j];
        float wf = (float)((unsigned)r0 >> 20) * IW;
        if (AFF) wacc += wf;
        _Float16 wh = (_Float16)wf;
        h2v wp = (h2v){wh, wh};
        uint4 u0 = hp[(size_t)(r0 & 0xFFFFF) * 16];
        ac0 = ash2(u0.x) * wp + ac0;
        ac1 = ash2(u0.y) * wp + ac1;
        ac2 = ash2(u0.z) * wp + ac2;
        ac3 = ash2(u0.w) * wp + ac3;
    }
    float a0 = (float)ac0[0], a1 = (float)ac0[1];
    float a2 = (float)ac1[0], a3 = (float)ac1[1];
    float a4 = (float)ac2[0], a5 = (float)ac2[1];
    float a6 = (float)ac3[0], a7 = (float)ac3[1];
    float scl = dri[node];
    if (AFF) {
        const float* ap = &lss[lq * 8];
        const float* bp = &lss[128 + lq * 8];
        a0 = ap[0] * a0 + bp[0] * wacc;
        a1 = ap[1] * a1 + bp[1] * wacc;
        a2 = ap[2] * a2 + bp[2] * wacc;
        a3 = ap[3] * a3 + bp[3] * wacc;
        a4 = ap[4] * a4 + bp[4] * wacc;
        a5 = ap[5] * a5 + bp[5] * wacc;
        a6 = ap[6] * a6 + bp[6] * wacc;
        a7 = ap[7] * a7 + bp[7] * wacc;
    }
    uint4 o;
    o.x = packh2(a0 * scl, a1 * scl);
    o.y = packh2(a2 * scl, a3 * scl);
    o.z = packh2(a4 * scl, a5 * scl);
    o.w = packh2(a6 * scl, a7 * scl);
    ((uint4*)z)[(size_t)node * 16 + lq] = o;
}

// ---------------- fused layer GEMM: gc (K=384) -> LDS -> fc + ReLU + BN ----
// 512 threads / 8 waves; wave tile 32 rows x 64 cols. fp16 MFMA.
// gcout tile lives in swizzled LDS (chunk' = chunk ^ (row&15), 16B chunks).
// MODE 0: write fp16 pre-BN h into outb; MODE 1: write fp32 into outf.
template <int MODE>
__launch_bounds__(512)
__global__ void mfma_layer(const unsigned short* __restrict__ zB,
                           const unsigned short* __restrict__ Wgp,
                           const float* __restrict__ b3,
                           const unsigned short* __restrict__ Wfp,
                           const float* __restrict__ fcb,
                           unsigned short* __restrict__ outb, float* __restrict__ outf,
                           float* __restrict__ bnsum, int M) {
    __shared__ unsigned short T[128 * 128];   // swizzled gcout tile (32KB)
    __shared__ float red[256];
    const int tid = threadIdx.x;
    const int l = tid & 63;
    const int wv = tid >> 6;          // 0..7
    const int wm = wv >> 1;           // 0..3 (row group of 32)
    const int wn = wv & 1;            // 0..1 (col group of 64)
    const int m0 = blockIdx.x * 128;
    const int lr = l & 15;
    const int lk = (l >> 4) * 8;

    int rowb[2];
#pragma unroll
    for (int mt = 0; mt < 2; ++mt) {
        int r = m0 + wm * 32 + mt * 16 + lr;
        rowb[mt] = (r < M) ? r : (M - 1);
    }

    // ---- phase 1: gcout = [z0|z1|z2] @ Wg + sum(bias) ----
    {
        f4v acc[2][4];
#pragma unroll
        for (int i = 0; i < 2; ++i)
#pragma unroll
            for (int j = 0; j < 4; ++j) acc[i][j] = (f4v){0.f, 0.f, 0.f, 0.f};
#pragma unroll
        for (int e = 0; e < 3; ++e) {
            const unsigned short* zp = zB + (size_t)e * M * 128;
            const unsigned short* wp = Wgp + (size_t)e * 16384;
#pragma unroll
            for (int ks = 0; ks < 4; ++ks) {
                f16x8 a[2], b[4];
#pragma unroll
                for (int mt = 0; mt < 2; ++mt)
                    a[mt] = *(const f16x8*)(zp + (size_t)rowb[mt] * 128 + ks * 32 + lk);
#pragma unroll
                for (int nt = 0; nt < 4; ++nt)
                    b[nt] = *(const f16x8*)(wp + ks * 4096 + (wn * 4 + nt) * 512 + l * 8);
#pragma unroll
                for (int mt = 0; mt < 2; ++mt)
#pragma unroll
                    for (int nt = 0; nt < 4; ++nt)
                        acc[mt][nt] = __builtin_amdgcn_mfma_f32_16x16x32_f16(
                            a[mt], b[nt], acc[mt][nt], 0, 0, 0);
            }
        }
        float bs[4];
        int col[4];
#pragma unroll
        for (int nt = 0; nt < 4; ++nt) {
            col[nt] = wn * 64 + nt * 16 + lr;
            bs[nt] = b3[col[nt]] + b3[128 + col[nt]] + b3[256 + col[nt]];
        }
        // write tile to swizzled LDS (all local rows, even M-clamped ones)
#pragma unroll
        for (int mt = 0; mt < 2; ++mt) {
#pragma unroll
            for (int r = 0; r < 4; ++r) {
                int rl = wm * 32 + mt * 16 + (l >> 4) * 4 + r;
#pragma unroll
                for (int nt = 0; nt < 4; ++nt) {
                    int c = col[nt];
                    int chunk = (c >> 3) ^ (rl & 15);
                    T[rl * 128 + chunk * 8 + (c & 7)] = f16b(acc[mt][nt][r] + bs[nt]);
                }
            }
        }
    }
    __syncthreads();

    // ---- phase 2: h = relu(gcout @ Wf + fcb), BN stats ----
    f4v acc2[2][4];
#pragma unroll
    for (int i = 0; i < 2; ++i)
#pragma unroll
        for (int j = 0; j < 4; ++j) acc2[i][j] = (f4v){0.f, 0.f, 0.f, 0.f};
#pragma unroll
    for (int ks = 0; ks < 4; ++ks) {
        f16x8 a[2], b[4];
#pragma unroll
        for (int mt = 0; mt < 2; ++mt) {
            int rl = wm * 32 + mt * 16 + lr;
            int chunk = (ks * 4 + (l >> 4)) ^ lr;   // rl & 15 == lr
            a[mt] = *(const f16x8*)&T[rl * 128 + chunk * 8];
        }
#pragma unroll
        for (int nt = 0; nt < 4; ++nt)
            b[nt] = *(const f16x8*)(Wfp + ks * 4096 + (wn * 4 + nt) * 512 + l * 8);
#pragma unroll
        for (int mt = 0; mt < 2; ++mt)
#pragma unroll
            for (int nt = 0; nt < 4; ++nt)
                acc2[mt][nt] = __builtin_amdgcn_mfma_f32_16x16x32_f16(
                    a[mt], b[nt], acc2[mt][nt], 0, 0, 0);
    }

    float bv[4], cs[4] = {}, cq[4] = {};
    int col[4];
#pragma unroll
    for (int nt = 0; nt < 4; ++nt) {
        col[nt] = wn * 64 + nt * 16 + lr;
        bv[nt] = fcb[col[nt]];
    }
#pragma unroll
    for (int mt = 0; mt < 2; ++mt) {
#pragma unroll
        for (int r = 0; r < 4; ++r) {
            int row = m0 + wm * 32 + mt * 16 + (l >> 4) * 4 + r;
            if (row < M) {
#pragma unroll
                for (int nt = 0; nt < 4; ++nt) {
                    float v = acc2[mt][nt][r] + bv[nt];
                    v = v > 0.f ? v : 0.f;
                    cs[nt] += v;
                    cq[nt] += v * v;
                    if (MODE == 0)
                        outb[(size_t)row * 128 + col[nt]] = f16b(v);
                    else
                        outf[(size_t)row * 128 + col[nt]] = v;
                }
            }
        }
    }
    if (tid < 256) red[tid] = 0.f;
    __syncthreads();
#pragma unroll
    for (int nt = 0; nt < 4; ++nt) {
        atomicAdd(&red[col[nt]], cs[nt]);
        atomicAdd(&red[128 + col[nt]], cq[nt]);
    }
    __syncthreads();
    if (tid < 128) {
        atomicAdd(&bnsum[tid], red[tid]);
        atomicAdd(&bnsum[128 + tid], red[128 + tid]);
    }
}

// ---------------- final BN apply (fp32 out) --------------------------------
__global__ void bn_apply(float* __restrict__ h, const float* __restrict__ bnsum,
                         const float* __restrict__ gamma, const float* __restrict__ beta,
                         float invn, int total4) {
    __shared__ float lss[256];
    int tid = threadIdx.x;
    if (tid < 128) {
        float mean = bnsum[tid] * invn;
        float var = bnsum[128 + tid] * invn - mean * mean;
        float sc = gamma[tid] * rsqrtf(var + EPSV);
        lss[tid] = sc;
        lss[128 + tid] = beta[tid] - mean * sc;
    }
    __syncthreads();
    int i = blockIdx.x * 256 + tid;
    if (i >= total4) return;
    int c4 = (i & 31) * 4;
    float4 sc = *(const float4*)&lss[c4];
    float4 sh = *(const float4*)&lss[128 + c4];
    float4 v = ((float4*)h)[i];
    v.x = v.x * sc.x + sh.x;
    v.y = v.y * sc.y + sh.y;
    v.z = v.z * sc.z + sh.z;
    v.w = v.w * sc.w + sh.w;
    ((float4*)h)[i] = v;
}

// ---------------------------------------------------------------------------
extern "C" void kernel_launch(void* const* d_in, const int* in_sizes, int n_in,
                              void* d_out, int out_size, void* d_ws, size_t ws_size,
                              hipStream_t stream) {
    const float* x    = (const float*)d_in[0];
    const int*   src  = (const int*)d_in[1];
    const int*   dst  = (const int*)d_in[2];
    const float* gcW0 = (const float*)d_in[3];
    const float* gcb0 = (const float*)d_in[4];
    const float* gcW  = (const float*)d_in[5];
    const float* gcb  = (const float*)d_in[6];
    const float* fcW  = (const float*)d_in[7];
    const float* fcb  = (const float*)d_in[8];
    const float* bng  = (const float*)d_in[9];
    const float* bnb  = (const float*)d_in[10];
    float* out = (float*)d_out;

    const int N = in_sizes[0] / 128;
    const int E = in_sizes[1] / 3;
    const int NB = (N + 255) / 256;   // <= MAXNB for this problem size
    const int nblk = (E + CH - 1) / CH;

    char* w = (char*)d_ws;
    auto alloc = [&](size_t bytes) -> char* {
        char* p = w;
        w += (bytes + 255) & ~(size_t)255;
        return p;
    };
    unsigned short* zB    = (unsigned short*)alloc((size_t)3 * N * 128 * 2);  // z0|z1|z2
    unsigned short* h2    = (unsigned short*)alloc((size_t)N * 128 * 2);
    unsigned short* Wg    = (unsigned short*)alloc((size_t)9 * 16384 * 2);
    unsigned short* Wf    = (unsigned short*)alloc((size_t)3 * 16384 * 2);
    int*   erec   = (int*)alloc((size_t)3 * E * 4);
    int*   rowptr = (int*)alloc((size_t)3 * (N + 1) * 4);
    float* dro    = (float*)alloc((size_t)3 * N * 4);
    float* dri    = (float*)alloc((size_t)3 * N * 4);
    int*   bhd    = (int*)alloc((size_t)3 * NB * nblk * 4);
    int*   bhs    = (int*)alloc((size_t)3 * NB * nblk * 4);
    int*   bpd    = (int*)alloc((size_t)3 * NB * nblk * 4);
    int*   bps    = (int*)alloc((size_t)3 * NB * nblk * 4);
    int*   chd    = (int*)alloc((size_t)3 * NB * 4);
    int*   chs    = (int*)alloc((size_t)3 * NB * 4);
    int*   offd   = (int*)alloc((size_t)3 * (NB + 1) * 4);
    int*   offs   = (int*)alloc((size_t)3 * (NB + 1) * 4);
    float* bnsum  = (float*)alloc(256 * 4);
    // build-only buffers alias zB (build completes before agg writes zB)
    int* dbuf = (int*)zB;                                  // 3E*4 = 19.2MB
    unsigned char* sbuf = (unsigned char*)(dbuf + (size_t)3 * E);  // 3E = 4.8MB (total 24MB <= 76.8MB)

    // ---- radix counting-sort CSR build (deterministic, atomic-free) ----
    dim3 cg2(nblk, 3);
    coarse_hist<<<cg2, 256, 0, stream>>>(src, dst, bhd, bhs, E, NB, nblk);
    blk_scan<<<(2 * 3 * NB + 255) / 256, 256, 0, stream>>>(bhd, bhs, bpd, bps, chd, chs, NB, nblk);
    scan_off<<<1, MAXNB, 0, stream>>>(chd, chs, offd, offs, rowptr, NB, N, E);
    scatter_coarse<<<cg2, 256, 0, stream>>>(src, dst, bhd, bhs, bpd, bps, offd, offs,
                                            dbuf, sbuf, E, NB, nblk);
    dim3 fg(NB, 3);
    fine_src<<<fg, 256, 0, stream>>>(sbuf, offs, dro, E, N, NB);          // dro first
    fine_dst<<<fg, 256, 0, stream>>>(dbuf, offd, dro, erec, rowptr, dri, E, N, NB);

    // ---- weight packing + initial fp16 x ----
    pack_w<<<12, 256, 0, stream>>>(gcW0, gcW, fcW, Wg, Wf);
    const int cvtGrid = (N * 16 + 255) / 256;
    cvt_f16<<<cvtGrid, 256, 0, stream>>>(x, h2, N * 16);

    // ---- layers ----
    const int gemmGrid = (N + 127) / 128;
    const float invn = 1.0f / (float)N;
    dim3 aggG((N * 16 + 255) / 256, 3);

    for (int l = 0; l < 3; ++l) {
        const float* bl = (l == 0) ? gcb0 : gcb + (size_t)(l - 1) * 3 * 128;
        if (l == 0)
            agg_kernel<0><<<aggG, 256, 0, stream>>>(h2, rowptr, erec, dri,
                                                    nullptr, nullptr, nullptr, invn,
                                                    zB, N, E);
        else
            agg_kernel<1><<<aggG, 256, 0, stream>>>(h2, rowptr, erec, dri,
                                                    bnsum, bng + (size_t)(l - 1) * 128,
                                                    bnb + (size_t)(l - 1) * 128, invn,
                                                    zB, N, E);
        hipMemsetAsync(bnsum, 0, 256 * 4, stream);
        if (l < 2)
            mfma_layer<0><<<gemmGrid, 512, 0, stream>>>(zB, Wg + (size_t)l * 3 * 16384, bl,
                                                        Wf + (size_t)l * 16384,
                                                        fcb + (size_t)l * 128,
                                                        h2, nullptr, bnsum, N);
        else
            mfma_layer<1><<<gemmGrid, 512, 0, stream>>>(zB, Wg + (size_t)l * 3 * 16384, bl,
                                                        Wf + (size_t)l * 16384,
                                                        fcb + (size_t)l * 128,
                                                        nullptr, out, bnsum, N);
    }
    bn_apply<<<(N * 32 + 255) / 256, 256, 0, stream>>>(out, bnsum, bng + 2 * 128,
                                                       bnb + 2 * 128, invn, N * 32);
}

// Round 15
// 875.356 us; speedup vs baseline: 1.2071x; 1.2071x over previous
//
#include <hip/hip_runtime.h>

// ---------------------------------------------------------------------------
// Encoder: 3-layer HeteroGraphConv(3 edge types) -> FC -> ReLU -> BatchNorm
// Round 15 (= R14 with blk_scan fixed):
//   * blk_scan was 195us: 3072 serial threads, uncoalesced stride-nblk reads.
//     Now one 256-thread block per (type,bin) row, LDS Hillis-Steele scan
//     over blocks (nblk=391 <= 512). ~8us.
//   * rest identical: radix build (atomic-free scatter), fp16 pipeline,
//     packed 4B records, fused mfma_layer
// ---------------------------------------------------------------------------

#define EPSV 1e-5f
#define CH 4096      // edges per block in coarse passes
#define MAXNB 512    // max coarse bins (N <= 131072; also requires N < 2^20)

typedef _Float16 h2v __attribute__((ext_vector_type(2)));
typedef _Float16 f16x8 __attribute__((ext_vector_type(8)));  // MFMA A/B frag
typedef __attribute__((ext_vector_type(4))) float f4v;       // 4 f32 acc

// ---------------- build phase 1: per-block coarse histograms ---------------
__global__ void coarse_hist(const int* __restrict__ src, const int* __restrict__ dst,
                            int* __restrict__ bhd, int* __restrict__ bhs,
                            int E, int NB, int nblk) {
    __shared__ int hd[MAXNB], hs[MAXNB];
    const int t = blockIdx.y;
    const int blk = blockIdx.x;
    for (int i = threadIdx.x; i < MAXNB; i += 256) { hd[i] = 0; hs[i] = 0; }
    __syncthreads();
    int base = blk * CH;
    int end = base + CH < E ? base + CH : E;
    const int* sp = src + (size_t)t * E;
    const int* dp = dst + (size_t)t * E;
    for (int i = base + threadIdx.x; i < end; i += 256) {
        atomicAdd(&hd[dp[i] >> 8], 1);
        atomicAdd(&hs[sp[i] >> 8], 1);
    }
    __syncthreads();
    for (int b = threadIdx.x; b < NB; b += 256) {
        size_t o = (size_t)(t * NB + b) * nblk + blk;
        bhd[o] = hd[b];
        bhs[o] = hs[b];
    }
}

// ---------------- build phase 2a: prefix over blocks per (type,bin) --------
// one block per (type,bin) row; parallel LDS scan over nblk (<=512) blocks.
__global__ void blk_scan(const int* __restrict__ bhd, const int* __restrict__ bhs,
                         int* __restrict__ bpd, int* __restrict__ bps,
                         int* __restrict__ chd, int* __restrict__ chs,
                         int NB, int nblk) {
    __shared__ int s[MAXNB];
    const int half = 3 * NB;
    const int id = blockIdx.x;                 // 0 .. 2*3*NB-1
    const bool isS = id >= half;
    const int r = isS ? id - half : id;
    const int* cnt = isS ? bhs : bhd;
    int* pfx = isS ? bps : bpd;
    int* tot = isS ? chs : chd;
    const size_t base = (size_t)r * nblk;
    const int tid = threadIdx.x;
    int v0 = (tid < nblk) ? cnt[base + tid] : 0;
    int v1 = (tid + 256 < nblk) ? cnt[base + tid + 256] : 0;
    s[tid] = v0;
    s[tid + 256] = v1;
    __syncthreads();
    for (int o = 1; o < MAXNB; o <<= 1) {
        int a0 = s[tid], a1 = s[tid + 256];
        int p0 = (tid >= o) ? s[tid - o] : 0;
        int p1 = s[tid + 256 - o];
        __syncthreads();
        s[tid] = a0 + p0;
        s[tid + 256] = a1 + p1;
        __syncthreads();
    }
    if (tid < nblk) pfx[base + tid] = s[tid] - v0;
    if (tid + 256 < nblk) pfx[base + tid + 256] = s[tid + 256] - v1;
    if (tid == 0) tot[r] = s[nblk - 1];
}

// ---------------- build phase 2b: scan coarse bins -> offsets --------------
__global__ void scan_off(const int* __restrict__ chd, const int* __restrict__ chs,
                         int* __restrict__ offd, int* __restrict__ offs,
                         int* __restrict__ rowptr, int NB, int N, int E) {
    __shared__ int s[MAXNB];
    int tid = threadIdx.x;
    for (int a = 0; a < 6; ++a) {
        const int* h = (a < 3) ? chd + a * NB : chs + (a - 3) * NB;
        int* off = (a < 3) ? offd + a * (NB + 1) : offs + (a - 3) * (NB + 1);
        s[tid] = (tid < NB) ? h[tid] : 0;
        __syncthreads();
        for (int o = 1; o < MAXNB; o <<= 1) {
            int v = (tid >= o) ? s[tid - o] : 0;
            __syncthreads();
            s[tid] += v;
            __syncthreads();
        }
        if (tid < NB) {
            off[tid + 1] = s[tid];
            if (tid == 0) off[0] = 0;
        }
        __syncthreads();
    }
    if (tid < 3) rowptr[tid * (N + 1) + N] = E;
}

// ---------------- build phase 3: scatter (single pass, no atomics) ---------
__launch_bounds__(256)
__global__ void scatter_coarse(const int* __restrict__ src, const int* __restrict__ dst,
                               const int* __restrict__ bhd, const int* __restrict__ bhs,
                               const int* __restrict__ bpd, const int* __restrict__ bps,
                               const int* __restrict__ offd, const int* __restrict__ offs,
                               int* __restrict__ dbuf, unsigned char* __restrict__ sbuf,
                               int E, int NB, int nblk) {
    __shared__ int hd[MAXNB], hs[MAXNB];     // local cursors
    __shared__ int lod[MAXNB], los[MAXNB];   // inclusive scans
    __shared__ int bd[MAXNB], bs[MAXNB];     // global bases
    __shared__ int rbi[CH];
    __shared__ unsigned char rbs[CH];
    const int tid = threadIdx.x;
    const int t = blockIdx.y;
    const int blk = blockIdx.x;
    const int base = blk * CH;
    const int end = base + CH < E ? base + CH : E;
    const int cnt = end - base;
    const int* sp = src + (size_t)t * E;
    const int* dp = dst + (size_t)t * E;

    // load this block's counts + global bases
    for (int b = tid; b < MAXNB; b += 256) {
        if (b < NB) {
            size_t o = (size_t)(t * NB + b) * nblk + blk;
            int cd = bhd[o], cs2 = bhs[o];
            hd[b] = cd;
            hs[b] = cs2;
            bd[b] = offd[t * (NB + 1) + b] + bpd[o];
            bs[b] = offs[t * (NB + 1) + b] + bps[o];
        } else {
            hd[b] = 0;
            hs[b] = 0;
        }
    }
    lod[tid] = hd[tid]; lod[tid + 256] = hd[tid + 256];
    los[tid] = hs[tid]; los[tid + 256] = hs[tid + 256];
    __syncthreads();
    for (int o = 1; o < MAXNB; o <<= 1) {
        int a0 = lod[tid], a1 = lod[tid + 256];
        int b0 = los[tid], b1 = los[tid + 256];
        int p0 = (tid >= o) ? lod[tid - o] : 0;
        int p1 = lod[tid + 256 - o];
        int q0 = (tid >= o) ? los[tid - o] : 0;
        int q1 = los[tid + 256 - o];
        __syncthreads();
        lod[tid] = a0 + p0; lod[tid + 256] = a1 + p1;
        los[tid] = b0 + q0; los[tid + 256] = b1 + q1;
        __syncthreads();
    }
    hd[tid] = lod[tid] - hd[tid]; hd[tid + 256] = lod[tid + 256] - hd[tid + 256];
    hs[tid] = los[tid] - hs[tid]; hs[tid + 256] = los[tid + 256] - hs[tid + 256];
    __syncthreads();
    for (int i = base + tid; i < end; i += 256) {
        int sv = sp[i], dv = dp[i];
        int lp = atomicAdd(&hd[dv >> 8], 1);
        rbi[lp] = (sv << 8) | (dv & 255);
        int ls = atomicAdd(&hs[sv >> 8], 1);
        rbs[ls] = (unsigned char)(sv & 255);
    }
    __syncthreads();
    for (int i = tid; i < cnt; i += 256) {
        int lo = 0, hi = NB - 1;
        while (lo < hi) { int mid = (lo + hi) >> 1; if (lod[mid] > i) hi = mid; else lo = mid + 1; }
        int excl = lo ? lod[lo - 1] : 0;
        dbuf[(size_t)t * E + bd[lo] + (i - excl)] = rbi[i];
    }
    for (int i = tid; i < cnt; i += 256) {
        int lo = 0, hi = NB - 1;
        while (lo < hi) { int mid = (lo + hi) >> 1; if (los[mid] > i) hi = mid; else lo = mid + 1; }
        int excl = lo ? los[lo - 1] : 0;
        sbuf[(size_t)t * E + bs[lo] + (i - excl)] = rbs[i];
    }
}

// ---------------- build phase 4a: fine histogram by src -> dro (FIRST) -----
__global__ void fine_src(const unsigned char* __restrict__ sbuf, const int* __restrict__ offs,
                         float* __restrict__ dro, int E, int N, int NB) {
    __shared__ int h[256];
    int b = blockIdx.x, t = blockIdx.y;
    int tid = threadIdx.x;
    h[tid] = 0;
    __syncthreads();
    int beg = offs[t * (NB + 1) + b], end = offs[t * (NB + 1) + b + 1];
    const unsigned char* sp = sbuf + (size_t)t * E;
    for (int i = beg + tid; i < end; i += 256) atomicAdd(&h[sp[i]], 1);
    __syncthreads();
    int node = b * 256 + tid;
    if (node < N) {
        int dg = h[tid] < 1 ? 1 : h[tid];
        dro[(size_t)t * N + node] = rsqrtf((float)dg);
    }
}

// ---------------- build phase 4b: fine sort by dst -> records src|wq<<20 ---
#define FDCAP 6656
__global__ void fine_dst(const int* __restrict__ dbuf, const int* __restrict__ offd,
                         const float* __restrict__ dro, int* __restrict__ erec,
                         int* __restrict__ rowptr, float* __restrict__ dri,
                         int E, int N, int NB) {
    __shared__ int h[256], sc[256], cur[256];
    __shared__ int rb[FDCAP];
    int b = blockIdx.x, t = blockIdx.y;
    int tid = threadIdx.x;
    h[tid] = 0;
    __syncthreads();
    int beg = offd[t * (NB + 1) + b], end = offd[t * (NB + 1) + b + 1];
    int cnt = end - beg;
    const int* dp = dbuf + (size_t)t * E;
    const float* drt = dro + (size_t)t * N;
    for (int i = beg + tid; i < end; i += 256) atomicAdd(&h[dp[i] & 255], 1);
    __syncthreads();
    sc[tid] = h[tid];
    __syncthreads();
    for (int o = 1; o < 256; o <<= 1) {
        int v = (tid >= o) ? sc[tid - o] : 0;
        __syncthreads();
        sc[tid] += v;
        __syncthreads();
    }
    int excl = sc[tid] - h[tid];
    cur[tid] = excl;
    int node = b * 256 + tid;
    if (node < N) {
        rowptr[t * (N + 1) + node] = beg + excl;
        int dg = h[tid] < 1 ? 1 : h[tid];
        dri[(size_t)t * N + node] = rsqrtf((float)dg);
    }
    __syncthreads();
    if (cnt <= FDCAP) {
        for (int i = beg + tid; i < end; i += 256) {
            int v = dp[i];
            int p = atomicAdd(&cur[v & 255], 1);
            rb[p] = v >> 8;
        }
        __syncthreads();
        for (int i = tid; i < cnt; i += 256) {
            int sv = rb[i];
            int wq = (int)(drt[sv] * 4095.0f + 0.5f);   // 12-bit weight
            erec[(size_t)t * E + beg + i] = sv | (wq << 20);
        }
    } else {
        for (int i = beg + tid; i < end; i += 256) {
            int v = dp[i];
            int sv = v >> 8;
            int wq = (int)(drt[sv] * 4095.0f + 0.5f);
            int p = beg + atomicAdd(&cur[v & 255], 1);
            erec[(size_t)t * E + p] = sv | (wq << 20);
        }
    }
}

// ---------------- fp16 helpers ----------------
__device__ __forceinline__ h2v ash2(unsigned u) {
    union { unsigned u; h2v h; } c;
    c.u = u;
    return c.h;
}
__device__ __forceinline__ unsigned packh2(float lo, float hi) {
    union { h2v h; unsigned u; } c;
    c.h = (h2v){(_Float16)lo, (_Float16)hi};
    return c.u;
}
__device__ __forceinline__ unsigned short f16b(float f) {
    union { _Float16 h; unsigned short s; } c;
    c.h = (_Float16)f;
    return c.s;
}

// ---------------- fp32 -> fp16 convert (initial x copy) --------------------
__global__ void cvt_f16(const float* __restrict__ h, unsigned short* __restrict__ h2,
                        int total8) {
    int i = blockIdx.x * 256 + threadIdx.x;
    if (i >= total8) return;
    const float4* hp = (const float4*)h + (size_t)i * 2;
    float4 v0 = hp[0], v1 = hp[1];
    uint4 o;
    o.x = packh2(v0.x, v0.y);
    o.y = packh2(v0.z, v0.w);
    o.z = packh2(v1.x, v1.y);
    o.w = packh2(v1.z, v1.w);
    ((uint4*)h2)[i] = o;
}

// ---------------- weight packing: fragment-ordered fp16 --------------------
__global__ void pack_w(const float* __restrict__ gcW0, const float* __restrict__ gcW,
                       const float* __restrict__ fcW, unsigned short* __restrict__ Wg,
                       unsigned short* __restrict__ Wf) {
    int mat = blockIdx.x;   // 0..8 = gc (l*3+e), 9..11 = fc layer
    const float* srcp;
    unsigned short* dstp;
    if (mat < 9) {
        int l = mat / 3, e = mat % 3;
        srcp = (l == 0) ? gcW0 + (size_t)e * 16384
                        : gcW + ((size_t)(l - 1) * 3 + e) * 16384;
        dstp = Wg + (size_t)mat * 16384;
    } else {
        srcp = fcW + (size_t)(mat - 9) * 16384;
        dstp = Wf + (size_t)(mat - 9) * 16384;
    }
    for (int p = threadIdx.x; p < 16384; p += 256) {
        int j = p & 7;
        int ln = (p >> 3) & 63;
        int nt = (p >> 9) & 7;
        int ks = p >> 12;
        int k = ks * 32 + (ln >> 4) * 8 + j;
        int n = nt * 16 + (ln & 15);
        dstp[p] = f16b(srcp[k * 128 + n]);
    }
}

// ---------------- aggregation: fp16 gather, packed half2 FMA ---------------
// 16 lanes/node, uint4 (8 fp16) per lane. Records = src | wq<<20 (w = wq/4095).
// AFF==1: input h2 is PRE-BN; BN affine folded via linearity (wacc term).
template <int AFF>
__launch_bounds__(256)
__global__ void agg_kernel(const unsigned short* __restrict__ h2, const int* __restrict__ rowptrB,
                           const int* __restrict__ erecB, const float* __restrict__ driB,
                           const float* __restrict__ bnsum, const float* __restrict__ gamma,
                           const float* __restrict__ beta, float invn,
                           unsigned short* __restrict__ zB, int N, int E) {
    __shared__ float lss[256];
    if (AFF) {
        int tid = threadIdx.x;
        if (tid < 128) {
            float mean = bnsum[tid] * invn;
            float var = bnsum[128 + tid] * invn - mean * mean;
            float sc = gamma[tid] * rsqrtf(var + EPSV);
            lss[tid] = sc;
            lss[128 + tid] = beta[tid] - mean * sc;
        }
        __syncthreads();
    }
    const int e = blockIdx.y;
    const int* rowptr = rowptrB + e * (N + 1);
    const int* erec = erecB + (size_t)e * E;
    const float* dri = driB + (size_t)e * N;
    unsigned short* z = zB + (size_t)e * N * 128;

    int idx = blockIdx.x * 256 + threadIdx.x;
    int node = idx >> 4;
    int lq = idx & 15;
    if (node >= N) return;
    int beg = rowptr[node], end = rowptr[node + 1];
    const uint4* hp = (const uint4*)h2 + lq;   // row s at hp[s*16]
    h2v ac0 = (h2v)0, ac1 = (h2v)0, ac2 = (h2v)0, ac3 = (h2v)0;
    float wacc = 0.f;
    const float IW = 1.0f / 4095.0f;

    int j = beg;
    for (; j + 8 <= end; j += 8) {
        int r[8];
#pragma unroll
        for (int q = 0; q < 8; ++q) r[q] = erec[j + q];
        uint4 u[8];
#pragma unroll
        for (int q = 0; q < 8; ++q) u[q] = hp[(size_t)(r[q] & 0xFFFFF) * 16];
#pragma unroll
        for (int q = 0; q < 8; ++q) {
            float wf = (float)((unsigned)r[q] >> 20) * IW;
            if (AFF) wacc += wf;
            _Float16 wh = (_Float16)wf;
            h2v wp = (h2v){wh, wh};
            ac0 = ash2(u[q].x) * wp + ac0;
            ac1 = ash2(u[q].y) * wp + ac1;
            ac2 = ash2(u[q].z) * wp + ac2;
            ac3 = ash2(u[q].w) * wp + ac3;
        }
    }
    for (; j + 4 <= end; j += 4) {
        int r[4];
#pragma unroll
        for (int q = 0; q < 4; ++q) r[q] = erec[j + q];
        uint4 u[4];
#pragma unroll
        for (int q = 0; q < 4; ++q) u[q] = hp[(size_t)(r[q] & 0xFFFFF) * 16];
#pragma unroll
        for (int q = 0; q < 4; ++q) {
            float wf = (float)((unsigned)r[q] >> 20) * IW;
            if (AFF) wacc += wf;
            _Float16 wh = (_Float16)wf;
            h2v wp = (h2v){wh, wh};
            ac0 = ash2(u[q].x) * wp + ac0;
            ac1 = ash2(u[q].y) * wp + ac1;
            ac2 = ash2(u[q].z) * wp + ac2;
            ac3 = ash2(u[q].w) * wp + ac3;
        }
    }
    for (; j < end; ++j) {
        int r0 = erec[j];
        float wf = (float)((unsigned)r0 >> 20) * IW;
        if (AFF) wacc += wf;
        _Float16 wh = (_Float16)wf;
        h2v wp = (h2v){wh, wh};
        uint4 u0 = hp[(size_t)(r0 & 0xFFFFF) * 16];
        ac0 = ash2(u0.x) * wp + ac0;
        ac1 = ash2(u0.y) * wp + ac1;
        ac2 = ash2(u0.z) * wp + ac2;
        ac3 = ash2(u0.w) * wp + ac3;
    }
    float a0 = (float)ac0[0], a1 = (float)ac0[1];
    float a2 = (float)ac1[0], a3 = (float)ac1[1];
    float a4 = (float)ac2[0], a5 = (float)ac2[1];
    float a6 = (float)ac3[0], a7 = (float)ac3[1];
    float scl = dri[node];
    if (AFF) {
        const float* ap = &lss[lq * 8];
        const float* bp = &lss[128 + lq * 8];
        a0 = ap[0] * a0 + bp[0] * wacc;
        a1 = ap[1] * a1 + bp[1] * wacc;
        a2 = ap[2] * a2 + bp[2] * wacc;
        a3 = ap[3] * a3 + bp[3] * wacc;
        a4 = ap[4] * a4 + bp[4] * wacc;
        a5 = ap[5] * a5 + bp[5] * wacc;
        a6 = ap[6] * a6 + bp[6] * wacc;
        a7 = ap[7] * a7 + bp[7] * wacc;
    }
    uint4 o;
    o.x = packh2(a0 * scl, a1 * scl);
    o.y = packh2(a2 * scl, a3 * scl);
    o.z = packh2(a4 * scl, a5 * scl);
    o.w = packh2(a6 * scl, a7 * scl);
    ((uint4*)z)[(size_t)node * 16 + lq] = o;
}

// ---------------- fused layer GEMM: gc (K=384) -> LDS -> fc + ReLU + BN ----
// 512 threads / 8 waves; wave tile 32 rows x 64 cols. fp16 MFMA.
// gcout tile lives in swizzled LDS (chunk' = chunk ^ (row&15), 16B chunks).
// MODE 0: write fp16 pre-BN h into outb; MODE 1: write fp32 into outf.
template <int MODE>
__launch_bounds__(512)
__global__ void mfma_layer(const unsigned short* __restrict__ zB,
                           const unsigned short* __restrict__ Wgp,
                           const float* __restrict__ b3,
                           const unsigned short* __restrict__ Wfp,
                           const float* __restrict__ fcb,
                           unsigned short* __restrict__ outb, float* __restrict__ outf,
                           float* __restrict__ bnsum, int M) {
    __shared__ unsigned short T[128 * 128];   // swizzled gcout tile (32KB)
    __shared__ float red[256];
    const int tid = threadIdx.x;
    const int l = tid & 63;
    const int wv = tid >> 6;          // 0..7
    const int wm = wv >> 1;           // 0..3 (row group of 32)
    const int wn = wv & 1;            // 0..1 (col group of 64)
    const int m0 = blockIdx.x * 128;
    const int lr = l & 15;
    const int lk = (l >> 4) * 8;

    int rowb[2];
#pragma unroll
    for (int mt = 0; mt < 2; ++mt) {
        int r = m0 + wm * 32 + mt * 16 + lr;
        rowb[mt] = (r < M) ? r : (M - 1);
    }

    // ---- phase 1: gcout = [z0|z1|z2] @ Wg + sum(bias) ----
    {
        f4v acc[2][4];
#pragma unroll
        for (int i = 0; i < 2; ++i)
#pragma unroll
            for (int j = 0; j < 4; ++j) acc[i][j] = (f4v){0.f, 0.f, 0.f, 0.f};
#pragma unroll
        for (int e = 0; e < 3; ++e) {
            const unsigned short* zp = zB + (size_t)e * M * 128;
            const unsigned short* wp = Wgp + (size_t)e * 16384;
#pragma unroll
            for (int ks = 0; ks < 4; ++ks) {
                f16x8 a[2], b[4];
#pragma unroll
                for (int mt = 0; mt < 2; ++mt)
                    a[mt] = *(const f16x8*)(zp + (size_t)rowb[mt] * 128 + ks * 32 + lk);
#pragma unroll
                for (int nt = 0; nt < 4; ++nt)
                    b[nt] = *(const f16x8*)(wp + ks * 4096 + (wn * 4 + nt) * 512 + l * 8);
#pragma unroll
                for (int mt = 0; mt < 2; ++mt)
#pragma unroll
                    for (int nt = 0; nt < 4; ++nt)
                        acc[mt][nt] = __builtin_amdgcn_mfma_f32_16x16x32_f16(
                            a[mt], b[nt], acc[mt][nt], 0, 0, 0);
            }
        }
        float bs[4];
        int col[4];
#pragma unroll
        for (int nt = 0; nt < 4; ++nt) {
            col[nt] = wn * 64 + nt * 16 + lr;
            bs[nt] = b3[col[nt]] + b3[128 + col[nt]] + b3[256 + col[nt]];
        }
        // write tile to swizzled LDS (all local rows, even M-clamped ones)
#pragma unroll
        for (int mt = 0; mt < 2; ++mt) {
#pragma unroll
            for (int r = 0; r < 4; ++r) {
                int rl = wm * 32 + mt * 16 + (l >> 4) * 4 + r;
#pragma unroll
                for (int nt = 0; nt < 4; ++nt) {
                    int c = col[nt];
                    int chunk = (c >> 3) ^ (rl & 15);
                    T[rl * 128 + chunk * 8 + (c & 7)] = f16b(acc[mt][nt][r] + bs[nt]);
                }
            }
        }
    }
    __syncthreads();

    // ---- phase 2: h = relu(gcout @ Wf + fcb), BN stats ----
    f4v acc2[2][4];
#pragma unroll
    for (int i = 0; i < 2; ++i)
#pragma unroll
        for (int j = 0; j < 4; ++j) acc2[i][j] = (f4v){0.f, 0.f, 0.f, 0.f};
#pragma unroll
    for (int ks = 0; ks < 4; ++ks) {
        f16x8 a[2], b[4];
#pragma unroll
        for (int mt = 0; mt < 2; ++mt) {
            int rl = wm * 32 + mt * 16 + lr;
            int chunk = (ks * 4 + (l >> 4)) ^ lr;   // rl & 15 == lr
            a[mt] = *(const f16x8*)&T[rl * 128 + chunk * 8];
        }
#pragma unroll
        for (int nt = 0; nt < 4; ++nt)
            b[nt] = *(const f16x8*)(Wfp + ks * 4096 + (wn * 4 + nt) * 512 + l * 8);
#pragma unroll
        for (int mt = 0; mt < 2; ++mt)
#pragma unroll
            for (int nt = 0; nt < 4; ++nt)
                acc2[mt][nt] = __builtin_amdgcn_mfma_f32_16x16x32_f16(
                    a[mt], b[nt], acc2[mt][nt], 0, 0, 0);
    }

    float bv[4], cs[4] = {}, cq[4] = {};
    int col[4];
#pragma unroll
    for (int nt = 0; nt < 4; ++nt) {
        col[nt] = wn * 64 + nt * 16 + lr;
        bv[nt] = fcb[col[nt]];
    }
#pragma unroll
    for (int mt = 0; mt < 2; ++mt) {
#pragma unroll
        for (int r = 0; r < 4; ++r) {
            int row = m0 + wm * 32 + mt * 16 + (l >> 4) * 4 + r;
            if (row < M) {
#pragma unroll
                for (int nt = 0; nt < 4; ++nt) {
                    float v = acc2[mt][nt][r] + bv[nt];
                    v = v > 0.f ? v : 0.f;
                    cs[nt] += v;
                    cq[nt] += v * v;
                    if (MODE == 0)
                        outb[(size_t)row * 128 + col[nt]] = f16b(v);
                    else
                        outf[(size_t)row * 128 + col[nt]] = v;
                }
            }
        }
    }
    if (tid < 256) red[tid] = 0.f;
    __syncthreads();
#pragma unroll
    for (int nt = 0; nt < 4; ++nt) {
        atomicAdd(&red[col[nt]], cs[nt]);
        atomicAdd(&red[128 + col[nt]], cq[nt]);
    }
    __syncthreads();
    if (tid < 128) {
        atomicAdd(&bnsum[tid], red[tid]);
        atomicAdd(&bnsum[128 + tid], red[128 + tid]);
    }
}

// ---------------- final BN apply (fp32 out) --------------------------------
__global__ void bn_apply(float* __restrict__ h, const float* __restrict__ bnsum,
                         const float* __restrict__ gamma, const float* __restrict__ beta,
                         float invn, int total4) {
    __shared__ float lss[256];
    int tid = threadIdx.x;
    if (tid < 128) {
        float mean = bnsum[tid] * invn;
        float var = bnsum[128 + tid] * invn - mean * mean;
        float sc = gamma[tid] * rsqrtf(var + EPSV);
        lss[tid] = sc;
        lss[128 + tid] = beta[tid] - mean * sc;
    }
    __syncthreads();
    int i = blockIdx.x * 256 + tid;
    if (i >= total4) return;
    int c4 = (i & 31) * 4;
    float4 sc = *(const float4*)&lss[c4];
    float4 sh = *(const float4*)&lss[128 + c4];
    float4 v = ((float4*)h)[i];
    v.x = v.x * sc.x + sh.x;
    v.y = v.y * sc.y + sh.y;
    v.z = v.z * sc.z + sh.z;
    v.w = v.w * sc.w + sh.w;
    ((float4*)h)[i] = v;
}

// ---------------------------------------------------------------------------
extern "C" void kernel_launch(void* const* d_in, const int* in_sizes, int n_in,
                              void* d_out, int out_size, void* d_ws, size_t ws_size,
                              hipStream_t stream) {
    const float* x    = (const float*)d_in[0];
    const int*   src  = (const int*)d_in[1];
    const int*   dst  = (const int*)d_in[2];
    const float* gcW0 = (const float*)d_in[3];
    const float* gcb0 = (const float*)d_in[4];
    const float* gcW  = (const float*)d_in[5];
    const float* gcb  = (const float*)d_in[6];
    const float* fcW  = (const float*)d_in[7];
    const float* fcb  = (const float*)d_in[8];
    const float* bng  = (const float*)d_in[9];
    const float* bnb  = (const float*)d_in[10];
    float* out = (float*)d_out;

    const int N = in_sizes[0] / 128;
    const int E = in_sizes[1] / 3;
    const int NB = (N + 255) / 256;   // <= MAXNB for this problem size
    const int nblk = (E + CH - 1) / CH;   // <= MAXNB (parallel blk_scan req.)

    char* w = (char*)d_ws;
    auto alloc = [&](size_t bytes) -> char* {
        char* p = w;
        w += (bytes + 255) & ~(size_t)255;
        return p;
    };
    unsigned short* zB    = (unsigned short*)alloc((size_t)3 * N * 128 * 2);  // z0|z1|z2
    unsigned short* h2    = (unsigned short*)alloc((size_t)N * 128 * 2);
    unsigned short* Wg    = (unsigned short*)alloc((size_t)9 * 16384 * 2);
    unsigned short* Wf    = (unsigned short*)alloc((size_t)3 * 16384 * 2);
    int*   erec   = (int*)alloc((size_t)3 * E * 4);
    int*   rowptr = (int*)alloc((size_t)3 * (N + 1) * 4);
    float* dro    = (float*)alloc((size_t)3 * N * 4);
    float* dri    = (float*)alloc((size_t)3 * N * 4);
    int*   bhd    = (int*)alloc((size_t)3 * NB * nblk * 4);
    int*   bhs    = (int*)alloc((size_t)3 * NB * nblk * 4);
    int*   bpd    = (int*)alloc((size_t)3 * NB * nblk * 4);
    int*   bps    = (int*)alloc((size_t)3 * NB * nblk * 4);
    int*   chd    = (int*)alloc((size_t)3 * NB * 4);
    int*   chs    = (int*)alloc((size_t)3 * NB * 4);
    int*   offd   = (int*)alloc((size_t)3 * (NB + 1) * 4);
    int*   offs   = (int*)alloc((size_t)3 * (NB + 1) * 4);
    float* bnsum  = (float*)alloc(256 * 4);
    // build-only buffers alias zB (build completes before agg writes zB)
    int* dbuf = (int*)zB;                                  // 3E*4 = 19.2MB
    unsigned char* sbuf = (unsigned char*)(dbuf + (size_t)3 * E);  // 3E = 4.8MB (total 24MB <= 76.8MB)

    // ---- radix counting-sort CSR build (deterministic, atomic-free) ----
    dim3 cg2(nblk, 3);
    coarse_hist<<<cg2, 256, 0, stream>>>(src, dst, bhd, bhs, E, NB, nblk);
    blk_scan<<<2 * 3 * NB, 256, 0, stream>>>(bhd, bhs, bpd, bps, chd, chs, NB, nblk);
    scan_off<<<1, MAXNB, 0, stream>>>(chd, chs, offd, offs, rowptr, NB, N, E);
    scatter_coarse<<<cg2, 256, 0, stream>>>(src, dst, bhd, bhs, bpd, bps, offd, offs,
                                            dbuf, sbuf, E, NB, nblk);
    dim3 fg(NB, 3);
    fine_src<<<fg, 256, 0, stream>>>(sbuf, offs, dro, E, N, NB);          // dro first
    fine_dst<<<fg, 256, 0, stream>>>(dbuf, offd, dro, erec, rowptr, dri, E, N, NB);

    // ---- weight packing + initial fp16 x ----
    pack_w<<<12, 256, 0, stream>>>(gcW0, gcW, fcW, Wg, Wf);
    const int cvtGrid = (N * 16 + 255) / 256;
    cvt_f16<<<cvtGrid, 256, 0, stream>>>(x, h2, N * 16);

    // ---- layers ----
    const int gemmGrid = (N + 127) / 128;
    const float invn = 1.0f / (float)N;
    dim3 aggG((N * 16 + 255) / 256, 3);

    for (int l = 0; l < 3; ++l) {
        const float* bl = (l == 0) ? gcb0 : gcb + (size_t)(l - 1) * 3 * 128;
        if (l == 0)
            agg_kernel<0><<<aggG, 256, 0, stream>>>(h2, rowptr, erec, dri,
                                                    nullptr, nullptr, nullptr, invn,
                                                    zB, N, E);
        else
            agg_kernel<1><<<aggG, 256, 0, stream>>>(h2, rowptr, erec, dri,
                                                    bnsum, bng + (size_t)(l - 1) * 128,
                                                    bnb + (size_t)(l - 1) * 128, invn,
                                                    zB, N, E);
        hipMemsetAsync(bnsum, 0, 256 * 4, stream);
        if (l < 2)
            mfma_layer<0><<<gemmGrid, 512, 0, stream>>>(zB, Wg + (size_t)l * 3 * 16384, bl,
                                                        Wf + (size_t)l * 16384,
                                                        fcb + (size_t)l * 128,
                                                        h2, nullptr, bnsum, N);
        else
            mfma_layer<1><<<gemmGrid, 512, 0, stream>>>(zB, Wg + (size_t)l * 3 * 16384, bl,
                                                        Wf + (size_t)l * 16384,
                                                        fcb + (size_t)l * 128,
                                                        nullptr, out, bnsum, N);
    }
    bn_apply<<<(N * 32 + 255) / 256, 256, 0, stream>>>(out, bnsum, bng + 2 * 128,
                                                       bnb + 2 * 128, invn, N * 32);
}